// Round 16
// baseline (459.881 us; speedup 1.0000x reference)
//
#include <hip/hip_runtime.h>
#include <hip/hip_fp16.h>
#include <math.h>

#define TPB 256
#define PMAX 128       // max partitions
#define PSH 10         // partition = dst >> 10 (1024 nodes/partition; n <= 131072)
#define PW  1024       // nodes per partition
#define CHUNK 8192     // edges per block in count/scatter

__device__ __forceinline__ float leaky02(float x) { return x > 0.f ? x : 0.2f * x; }
__device__ __forceinline__ float eluf(float x) { return x > 0.f ? x : (expf(x) - 1.f); }

// ====================== CSR build + fused layer-1 transform ======================

__global__ __launch_bounds__(256) void count_t1_kernel(
    const int* __restrict__ dst, int E, int n, int nbC,
    int* __restrict__ counts,
    const float* __restrict__ x, const float* __restrict__ W1,
    const float* __restrict__ ad1,
    __half* __restrict__ h, float* __restrict__ adst) {
  if ((int)blockIdx.x < nbC) {
    __shared__ int lcnt[PMAX];
    int Etot = E + n;
    int c0 = blockIdx.x * CHUNK;
    int c1 = min(c0 + CHUNK, Etot);
    for (int j = threadIdx.x; j < PMAX; j += TPB) lcnt[j] = 0;
    __syncthreads();
    for (int idx = c0 + threadIdx.x; idx < c1; idx += TPB) {
      int dd = (idx < E) ? dst[idx] : (idx - E);
      atomicAdd(&lcnt[dd >> PSH], 1);
    }
    __syncthreads();
    for (int j = threadIdx.x; j < PMAX; j += TPB)
      counts[blockIdx.x * PMAX + j] = lcnt[j];
  } else {
    __shared__ float sW[96];
    __shared__ float sa[32];
    if (threadIdx.x < 96) sW[threadIdx.x] = W1[threadIdx.x];
    if (threadIdx.x < 32) sa[threadIdx.x] = ad1[threadIdx.x];
    __syncthreads();
    int i = (blockIdx.x - nbC) * blockDim.x + threadIdx.x;
    if (i >= n) return;
    float x0 = x[(size_t)i * 3], x1 = x[(size_t)i * 3 + 1], x2 = x[(size_t)i * 3 + 2];
    float hv[32];
#pragma unroll
    for (int j = 0; j < 32; j++) {
      float acc = x0 * sW[j] + x1 * sW[32 + j] + x2 * sW[64 + j];
      hv[j] = acc;
      h[(size_t)i * 32 + j] = __float2half_rn(acc);
    }
#pragma unroll
    for (int hh = 0; hh < 2; hh++) {
      float ad = 0.f;
#pragma unroll
      for (int c = 0; c < 16; c++) ad += hv[hh * 16 + c] * sa[hh * 16 + c];
      adst[i * 2 + hh] = ad;
    }
  }
}

__global__ __launch_bounds__(128) void pscan_kernel(const int* __restrict__ counts, int nbC,
                                                    int* __restrict__ pbase,
                                                    int* __restrict__ pcursor, int NP) {
  __shared__ int sums[PMAX];
  int p = threadIdx.x;
  int s = 0;
  for (int b = 0; b < nbC; b++) s += counts[b * PMAX + p];
  sums[p] = (p < NP) ? s : 0;
  __syncthreads();
  if (p == 0) {
    int acc = 0;
    for (int q = 0; q < NP; q++) { pbase[q] = acc; pcursor[q] = acc; acc += sums[q]; }
    pbase[NP] = acc;
  }
}

__global__ __launch_bounds__(256) void scatter_kernel(const int* __restrict__ src,
                                                      const int* __restrict__ dst,
                                                      int E, int n,
                                                      const int* __restrict__ counts,
                                                      int* __restrict__ pcursor,
                                                      unsigned* __restrict__ pstage) {
  __shared__ int lbase[PMAX];
  __shared__ int lcnt[PMAX];
  int Etot = E + n;
  int c0 = blockIdx.x * CHUNK;
  int c1 = min(c0 + CHUNK, Etot);
  for (int j = threadIdx.x; j < PMAX; j += TPB) {
    int c = counts[blockIdx.x * PMAX + j];
    lbase[j] = atomicAdd(&pcursor[j], c);
    lcnt[j] = 0;
  }
  __syncthreads();
  for (int idx = c0 + threadIdx.x; idx < c1; idx += TPB) {
    int ss, dd;
    if (idx < E) { ss = src[idx]; dd = dst[idx]; }
    else         { ss = dd = idx - E; }
    int p = dd >> PSH;
    int pos = lbase[p] + atomicAdd(&lcnt[p], 1);
    pstage[pos] = ((unsigned)ss << PSH) | (unsigned)(dd & (PW - 1));
  }
}

__global__ __launch_bounds__(1024) void build_csr_kernel(const unsigned* __restrict__ pstage,
                                                         const int* __restrict__ pbase,
                                                         int nvtx,
                                                         int* __restrict__ rowptr,
                                                         int* __restrict__ csr_src) {
  __shared__ int lhist[PW];
  __shared__ int lcur[PW];
  int t = threadIdx.x;
  int p = blockIdx.x;
  int base = pbase[p];
  int end = pbase[p + 1];
  int nodebase = p << PSH;
  lhist[t] = 0;
  __syncthreads();
  for (int i = base + t; i < end; i += 1024)
    atomicAdd(&lhist[pstage[i] & (PW - 1)], 1);
  __syncthreads();
  int v = lhist[t];
  lcur[t] = v;
  __syncthreads();
  for (int off = 1; off < 1024; off <<= 1) {
    int a = (t >= off) ? lcur[t - off] : 0;
    __syncthreads();
    lcur[t] += a;
    __syncthreads();
  }
  int acc = base + lcur[t] - v;
  __syncthreads();
  lcur[t] = acc;
  int node = nodebase + t;
  if (node < nvtx) rowptr[node] = acc;
  __syncthreads();
  for (int i = base + t; i < end; i += 1024) {
    unsigned w = pstage[i];
    int pos = atomicAdd(&lcur[w & (PW - 1)], 1);
    csr_src[pos] = (int)(w >> PSH);
  }
  if (p == (int)gridDim.x - 1 && t == 0) rowptr[nvtx] = end;
}

// ====================== node transform (h = x@W fp16 + adst logits) ======================

template<int IN, int OUT, int H>
__global__ void transform_kernel(const float* __restrict__ x, const float* __restrict__ W,
                                 const float* __restrict__ a_dst,
                                 __half* __restrict__ h, float* __restrict__ adst, int n) {
  __shared__ float sW[IN * OUT];
  __shared__ float sa[OUT];
  for (int i = threadIdx.x; i < IN * OUT; i += blockDim.x) sW[i] = W[i];
  if (threadIdx.x < OUT) sa[threadIdx.x] = a_dst[threadIdx.x];
  __syncthreads();
  int i = blockIdx.x * blockDim.x + threadIdx.x;
  if (i >= n) return;
  float xv[IN];
#pragma unroll
  for (int k = 0; k < IN; k++) xv[k] = x[(size_t)i * IN + k];
  float hv[OUT];
#pragma unroll
  for (int j = 0; j < OUT; j++) {
    float acc = 0.f;
#pragma unroll
    for (int k = 0; k < IN; k++) acc += xv[k] * sW[k * OUT + j];
    hv[j] = acc;
    h[(size_t)i * OUT + j] = __float2half_rn(acc);
  }
#pragma unroll
  for (int hh = 0; hh < H; hh++) {
    float ad = 0.f;
#pragma unroll
    for (int c = 0; c < 16; c++) ad += hv[hh * 16 + c] * sa[hh * 16 + c];
    adst[i * H + hh] = ad;
  }
}

// ====================== single-pass per-node GAT (1 wave / dst node) ======================
// Each 8-lane group owns one edge: load the 64B fp16 h-row ONCE, derive the a_src logit from
// it (4 FMA + 2 intra-group shfl), w = exp(leaky(dot+adst)) [unshifted softmax, R12-verified],
// accumulate w*h from the same registers. No LDS, no separate asrc gather, no second pass.
// Intra-group shfls are exec-safe: loop bounds are uniform within each 8-lane group.

__global__ __launch_bounds__(256) void node_gat12(
    const int* __restrict__ rowptr,
    const int* __restrict__ csr_src,
    const float* __restrict__ adst,   // [n*2]
    const __half* __restrict__ hfeat, // [n*32] fp16
    const float* __restrict__ aSrc,   // [32] fp32
    const float* __restrict__ bias,   // [32]
    float* __restrict__ outb,         // [n*32] fp32
    int n) {
  int lane = threadIdx.x & 63;
  int i = (blockIdx.x * blockDim.x + threadIdx.x) >> 6;
  if (i >= n) return;
  int start = rowptr[i];
  int d = rowptr[i + 1] - start;
  float2 adv = ((const float2*)adst)[i];
  int g = lane >> 3;   // edge group 0..7
  int q = lane & 7;    // slot: channels 4q..4q+3 (q<4: head0, q>=4: head1)
  float4 av = ((const float4*)aSrc)[q];
  float ad = (q >= 4) ? adv.y : adv.x;
  const uint2* hf = (const uint2*)hfeat;
  const int* cs = csr_src + start;
  float4 acc = make_float4(0.f, 0.f, 0.f, 0.f);
  float sl = 0.f;

  for (int jj = g; jj < d; jj += 8) {
    int sb = cs[jj];                         // broadcast within group (1 line/wave)
    uint2 raw = hf[(size_t)sb * 8 + q];      // 8 lanes cover the 64B row -> 1 line/edge
    float2 f01 = __half22float2(*reinterpret_cast<const __half2*>(&raw.x));
    float2 f23 = __half22float2(*reinterpret_cast<const __half2*>(&raw.y));
    float dp = f01.x * av.x + f01.y * av.y + f23.x * av.z + f23.y * av.w;
    dp += __shfl_xor(dp, 1);
    dp += __shfl_xor(dp, 2);                 // full 16-ch a_src dot for my head
    float w = expf(leaky02(dp + ad));
    sl += w;
    acc.x += w * f01.x; acc.y += w * f01.y; acc.z += w * f23.x; acc.w += w * f23.y;
  }

  // reduce across the 8 edge-groups (q fixed)
#pragma unroll
  for (int off = 8; off <= 32; off <<= 1) {
    acc.x += __shfl_xor(acc.x, off);
    acc.y += __shfl_xor(acc.y, off);
    acc.z += __shfl_xor(acc.z, off);
    acc.w += __shfl_xor(acc.w, off);
    sl    += __shfl_xor(sl, off);
  }
  if (lane < 8) {
    float inv = 1.f / (sl + 1e-16f);
    float4 bv = ((const float4*)bias)[lane];
    float4 o;
    o.x = eluf(acc.x * inv + bv.x);
    o.y = eluf(acc.y * inv + bv.y);
    o.z = eluf(acc.z * inv + bv.z);
    o.w = eluf(acc.w * inv + bv.w);
    ((float4*)outb)[(size_t)i * 8 + lane] = o;
  }
}

// Layer 3 (16ch, H=1) + fused output head. 4-lane groups, 16 edges/iteration.
__global__ __launch_bounds__(256) void node_gat3(
    const int* __restrict__ rowptr,
    const int* __restrict__ csr_src,
    const float* __restrict__ adst,   // [n]
    const __half* __restrict__ hfeat, // [n*16] fp16
    const float* __restrict__ aSrc,   // [16]
    const float* __restrict__ b3,     // [16]
    const float* __restrict__ Wout,   // [16]
    const float* __restrict__ bout,   // [1]
    float* __restrict__ out,          // [n] sigmoid ++ [n*16] embeddings
    int n) {
  int lane = threadIdx.x & 63;
  int i = (blockIdx.x * blockDim.x + threadIdx.x) >> 6;
  if (i >= n) return;
  int start = rowptr[i];
  int d = rowptr[i + 1] - start;
  float ad = adst[i];
  int g = lane >> 2;   // edge group 0..15
  int q = lane & 3;    // slot: channels 4q..4q+3
  float4 av = ((const float4*)aSrc)[q];
  const uint2* hf = (const uint2*)hfeat;
  const int* cs = csr_src + start;
  float4 acc = make_float4(0.f, 0.f, 0.f, 0.f);
  float sl = 0.f;

  for (int jj = g; jj < d; jj += 16) {
    int sb = cs[jj];
    uint2 raw = hf[(size_t)sb * 4 + q];
    float2 f01 = __half22float2(*reinterpret_cast<const __half2*>(&raw.x));
    float2 f23 = __half22float2(*reinterpret_cast<const __half2*>(&raw.y));
    float dp = f01.x * av.x + f01.y * av.y + f23.x * av.z + f23.y * av.w;
    dp += __shfl_xor(dp, 1);
    dp += __shfl_xor(dp, 2);
    float w = expf(leaky02(dp + ad));
    sl += w;
    acc.x += w * f01.x; acc.y += w * f01.y; acc.z += w * f23.x; acc.w += w * f23.y;
  }

#pragma unroll
  for (int off = 4; off <= 32; off <<= 1) {
    acc.x += __shfl_xor(acc.x, off);
    acc.y += __shfl_xor(acc.y, off);
    acc.z += __shfl_xor(acc.z, off);
    acc.w += __shfl_xor(acc.w, off);
    sl    += __shfl_xor(sl, off);
  }
  float z = 0.f;
  if (lane < 4) {
    float inv = 1.f / (sl + 1e-16f);
    float4 bv = ((const float4*)b3)[lane];
    float4 wv = ((const float4*)Wout)[lane];
    float4 o;
    o.x = eluf(acc.x * inv + bv.x);
    o.y = eluf(acc.y * inv + bv.y);
    o.z = eluf(acc.z * inv + bv.z);
    o.w = eluf(acc.w * inv + bv.w);
    ((float4*)(out + n))[(size_t)i * 4 + lane] = o;
    z = o.x * wv.x + o.y * wv.y + o.z * wv.z + o.w * wv.w;
  }
  z += __shfl_xor(z, 1);
  z += __shfl_xor(z, 2);
  if (lane == 0) out[i] = 1.f / (1.f + expf(-(z + bout[0])));
}

// ====================== launch ======================

extern "C" void kernel_launch(void* const* d_in, const int* in_sizes, int n_in,
                              void* d_out, int out_size, void* d_ws, size_t ws_size,
                              hipStream_t stream) {
  const float* x    = (const float*)d_in[0];
  const int*   ei   = (const int*)d_in[1];
  const float* W1   = (const float*)d_in[2];
  const float* as1  = (const float*)d_in[3];
  const float* ad1  = (const float*)d_in[4];
  const float* b1   = (const float*)d_in[5];
  const float* W2   = (const float*)d_in[6];
  const float* as2  = (const float*)d_in[7];
  const float* ad2  = (const float*)d_in[8];
  const float* b2   = (const float*)d_in[9];
  const float* W3   = (const float*)d_in[10];
  const float* as3  = (const float*)d_in[11];
  const float* ad3  = (const float*)d_in[12];
  const float* b3   = (const float*)d_in[13];
  const float* Wout = (const float*)d_in[14];
  const float* bout = (const float*)d_in[15];
  float* out = (float*)d_out;

  const int n = in_sizes[0] / 3;
  const int E = in_sizes[1] / 2;
  const int Etot = E + n;
  const int* src = ei;
  const int* dst = ei + E;
  const int NP = ((n - 1) >> PSH) + 1;   // n=100000 -> 98 partitions
  const int nbC = (Etot + CHUNK - 1) / CHUNK;
  const int nbN = (n + TPB - 1) / TPB;
  const int nbW = (n + 3) / 4;

  // workspace: hH | bufX (pstage aliases bufX region; dead after build_csr) | adst | csr ...
  float* ws = (float*)d_ws;
  __half* hH  = (__half*)ws;                            // n*32 half
  float* bufX = ws + (size_t)n * 16;                    // n*32 f
  unsigned* pstage = (unsigned*)(ws + (size_t)n * 16);  // Etot uints (aliases bufX)
  size_t post = (size_t)n * 16 + ((size_t)Etot > (size_t)n * 32 ? (size_t)Etot : (size_t)n * 32);
  float* adst = ws + post;                              // n*2
  int* rowptr  = (int*)(adst + (size_t)n * 2);          // n+1
  int* pbase   = rowptr + n + 1;                        // PMAX+1
  int* pcursor = pbase + PMAX + 1;                      // PMAX
  int* csr_src = pcursor + PMAX;                        // Etot
  int* counts  = csr_src + Etot;                        // nbC*PMAX

  // ---- CSR build (+ fused layer-1 transform) ----
  count_t1_kernel<<<nbC + nbN, TPB, 0, stream>>>(dst, E, n, nbC, counts,
                                                 x, W1, ad1, hH, adst);
  pscan_kernel<<<1, PMAX, 0, stream>>>(counts, nbC, pbase, pcursor, NP);
  scatter_kernel<<<nbC, TPB, 0, stream>>>(src, dst, E, n, counts, pcursor, pstage);
  build_csr_kernel<<<NP, 1024, 0, stream>>>(pstage, pbase, n, rowptr, csr_src);

  // ---- layer 1 GAT ----
  node_gat12<<<nbW, TPB, 0, stream>>>(rowptr, csr_src, adst, hH, as1, b1, bufX, n);
  // ---- layer 2 ----
  transform_kernel<32, 32, 2><<<nbN, TPB, 0, stream>>>(bufX, W2, ad2, hH, adst, n);
  node_gat12<<<nbW, TPB, 0, stream>>>(rowptr, csr_src, adst, hH, as2, b2, bufX, n);
  // ---- layer 3 ----
  transform_kernel<32, 16, 1><<<nbN, TPB, 0, stream>>>(bufX, W3, ad3, hH, adst, n);
  node_gat3<<<nbW, TPB, 0, stream>>>(rowptr, csr_src, adst, hH, as3, b3, Wout, bout, out, n);
}